// Round 6
// baseline (1620.823 us; speedup 1.0000x reference)
//
#include <hip/hip_runtime.h>
#include <hip/hip_bf16.h>

// Sinkhorn on MI355X. B=64, L=1024, D=256.
// prep (norms + minmax init) -> gemm (K=exp(cos-1) fp16)
//   -> ktu0 (p0 = column sums, u0=1)
//   -> 10x fused F: v=w2/(reduce p + eps); z=Kv; u=w1/(z+eps); p'=partials(K^T u)
//   -> fin (out = minmax-norm(u*K*v^T) * (-log K))
// fp16 strip partials, DIRECT stores (no atomics — R5 showed atomics +290us).
// 1024-thread blocks on iteration passes: 16 waves/CU (4/SIMD) for latency.
// WS_NEED = 135791104 <= proven-available 136053248 (R2/R3).

#define EPSV 1e-12f
#define W1 0.0009765625f   // 1/1024

typedef short  short8 __attribute__((ext_vector_type(8)));
typedef float  f32x4  __attribute__((ext_vector_type(4)));
typedef _Float16 h8   __attribute__((ext_vector_type(8)));

// load 8 consecutive floats, convert to 8 bf16 (hw v_cvt_pk_bf16_f32)
__device__ __forceinline__ short8 ld_cvt8(const float* p) {
  float4 f0 = *(const float4*)p;
  float4 f1 = *(const float4*)(p + 4);
  float2 p0; p0.x = f0.x; p0.y = f0.y;
  float2 p1; p1.x = f0.z; p1.y = f0.w;
  float2 p2; p2.x = f1.x; p2.y = f1.y;
  float2 p3; p3.x = f1.z; p3.y = f1.w;
  __hip_bfloat162 h0 = __float22bfloat162_rn(p0);
  __hip_bfloat162 h1 = __float22bfloat162_rn(p1);
  __hip_bfloat162 h2_ = __float22bfloat162_rn(p2);
  __hip_bfloat162 h3 = __float22bfloat162_rn(p3);
  short2 a = *(short2*)&h0, b = *(short2*)&h1, c = *(short2*)&h2_, d = *(short2*)&h3;
  short8 r;
  r[0] = a.x; r[1] = a.y; r[2] = b.x; r[3] = b.y;
  r[4] = c.x; r[5] = c.y; r[6] = d.x; r[7] = d.y;
  return r;
}

// ---------------------------------------------------------------- diag
__global__ __launch_bounds__(256) void diag_kernel(float* __restrict__ out,
                                                   float val, int n) {
  int stride = gridDim.x * 256;
  for (int i = blockIdx.x * 256 + threadIdx.x; i < n; i += stride) out[i] = val;
}

// ---------------------------------------------------------------- prep
// rows 0..65535 -> x1 norms, 65536..131071 -> x2 norms. 1 wave/row.
__global__ __launch_bounds__(256) void prep_kernel(
    const float* __restrict__ x1, const float* __restrict__ x2,
    float* __restrict__ n1, float* __restrict__ n2,
    unsigned* __restrict__ mm) {
  int t = threadIdx.x, bid = blockIdx.x;
  if (bid == 0 && t < 128) mm[t] = (t < 64) ? 0u : 0x7f800000u;
  int row = bid * 4 + (t >> 6);
  int lane = t & 63;
  const float* xp; float* np_;
  int r = row;
  if (row < 65536) { xp = x1; np_ = n1; }
  else { r = row - 65536; xp = x2; np_ = n2; }
  float4 v = ((const float4*)(xp + (size_t)r * 256))[lane];
  float s = v.x * v.x + v.y * v.y + v.z * v.z + v.w * v.w;
  #pragma unroll
  for (int off = 1; off < 64; off <<= 1) s += __shfl_xor(s, off, 64);
  if (lane == 0) np_[r] = sqrtf(s);
}

// ---------------------------------------------------------------- gemm
// 128x128 tile, BK=64, 4 waves (2x2 of 64x64), mfma_f32_16x16x32_bf16.
__global__ __launch_bounds__(256) void gemm_kernel(
    const float* __restrict__ x1, const float* __restrict__ x2,
    const float* __restrict__ n1, const float* __restrict__ n2,
    _Float16* __restrict__ Kh) {
  __shared__ __align__(16) unsigned short smem[2 * 128 * 64];  // 32 KB
  unsigned short* As = smem;
  unsigned short* Bs = smem + 128 * 64;
  int bid = blockIdx.x;
  int b = bid >> 6, tile = bid & 63;
  int ti = (tile >> 3) << 7, tj = (tile & 7) << 7;
  int t = threadIdx.x, lane = t & 63, wave = t >> 6;
  int wr = (wave >> 1) << 6, wc = (wave & 1) << 6;
  const float* Ag = x1 + ((size_t)(b * 1024 + ti)) * 256;
  const float* Bg = x2 + ((size_t)(b * 1024 + tj)) * 256;

  f32x4 acc[4][4];
  f32x4 zero = {0.f, 0.f, 0.f, 0.f};
  #pragma unroll
  for (int m = 0; m < 4; ++m)
    #pragma unroll
    for (int n = 0; n < 4; ++n) acc[m][n] = zero;

  short8 ra[4], rb[4];
  #pragma unroll
  for (int c = 0; c < 4; ++c) {
    int ch = t + (c << 8); int row = ch >> 3, kg = ch & 7;
    ra[c] = ld_cvt8(Ag + row * 256 + kg * 8);
    rb[c] = ld_cvt8(Bg + row * 256 + kg * 8);
  }

  for (int k0 = 0; k0 < 4; ++k0) {
    __syncthreads();
    #pragma unroll
    for (int c = 0; c < 4; ++c) {
      int ch = t + (c << 8); int row = ch >> 3, kg = ch & 7;
      int kgs = kg ^ (row & 7);
      *(short8*)(As + row * 64 + kgs * 8) = ra[c];
      *(short8*)(Bs + row * 64 + kgs * 8) = rb[c];
    }
    __syncthreads();
    if (k0 < 3) {
      #pragma unroll
      for (int c = 0; c < 4; ++c) {
        int ch = t + (c << 8); int row = ch >> 3, kg = ch & 7;
        ra[c] = ld_cvt8(Ag + row * 256 + (k0 + 1) * 64 + kg * 8);
        rb[c] = ld_cvt8(Bg + row * 256 + (k0 + 1) * 64 + kg * 8);
      }
    }
    #pragma unroll
    for (int ks = 0; ks < 2; ++ks) {
      short8 af[4], bfr[4];
      #pragma unroll
      for (int m = 0; m < 4; ++m) {
        int row = wr + m * 16 + (lane & 15);
        int c16 = (ks << 2) + (lane >> 4);
        af[m] = *(const short8*)(As + row * 64 + ((c16 ^ (row & 7)) << 3));
      }
      #pragma unroll
      for (int n = 0; n < 4; ++n) {
        int row = wc + n * 16 + (lane & 15);
        int c16 = (ks << 2) + (lane >> 4);
        bfr[n] = *(const short8*)(Bs + row * 64 + ((c16 ^ (row & 7)) << 3));
      }
      #pragma unroll
      for (int m = 0; m < 4; ++m)
        #pragma unroll
        for (int n = 0; n < 4; ++n)
          acc[m][n] = __builtin_amdgcn_mfma_f32_16x16x32_bf16(af[m], bfr[n], acc[m][n], 0, 0, 0);
    }
  }
  __syncthreads();

  // epilogue: cos -> K=exp(cos-1) fp16, repack via LDS for coalesced stores
  _Float16* Ct = (_Float16*)smem;  // 128*128 halves = 32 KB
  float a1v[4][4], b2v[4];
  #pragma unroll
  for (int m = 0; m < 4; ++m)
    #pragma unroll
    for (int q = 0; q < 4; ++q)
      a1v[m][q] = n1[(size_t)b * 1024 + ti + wr + m * 16 + ((lane >> 4) << 2) + q];
  #pragma unroll
  for (int n = 0; n < 4; ++n)
    b2v[n] = n2[(size_t)b * 1024 + tj + wc + n * 16 + (lane & 15)];
  #pragma unroll
  for (int m = 0; m < 4; ++m)
    #pragma unroll
    for (int n = 0; n < 4; ++n)
      #pragma unroll
      for (int q = 0; q < 4; ++q) {
        int rl = wr + m * 16 + ((lane >> 4) << 2) + q;
        int cl = wc + n * 16 + (lane & 15);
        float cosv = acc[m][n][q] / (a1v[m][q] * b2v[n] + EPSV);
        Ct[rl * 128 + cl] = (_Float16)__expf(cosv - 1.0f);
      }
  __syncthreads();
  size_t kbase = ((size_t)b << 20);
  #pragma unroll
  for (int c2i = 0; c2i < 8; ++c2i) {
    int c2 = t + (c2i << 8);
    int row = c2 >> 4, seg = c2 & 15;
    *(float4*)(Kh + kbase + (size_t)(ti + row) * 1024 + tj + seg * 8) = ((const float4*)Ct)[c2];
  }
}

// ---------------------------------------------------------------- ktu0
// p0 = column sums of K per 256-row strip (u0 = 1). block=(b, strip s of 4).
// 16 waves x 16 rows, batch-4 loads, register accumulators.
__global__ __launch_bounds__(1024, 4) void ktu0_kernel(
    const _Float16* __restrict__ Kh, _Float16* __restrict__ dst) {
  int bid = blockIdx.x;
  int b = bid >> 2, s = bid & 3;
  int t = threadIdx.x, lane = t & 63, w = t >> 6;
  __shared__ float plds[16][1024];  // 64 KB
  float pacc[16];
  #pragma unroll
  for (int k = 0; k < 16; ++k) pacc[k] = 0.f;
  const _Float16* kp = Kh + ((size_t)b << 20) + (size_t)(s * 256 + w) * 1024 + lane * 8;
  #pragma unroll
  for (int g = 0; g < 4; ++g) {
    h8 ka[4], kb[4];
    #pragma unroll
    for (int j = 0; j < 4; ++j) {
      int it = g * 4 + j;
      ka[j] = *(const h8*)(kp + (size_t)it * 16384);
      kb[j] = *(const h8*)(kp + (size_t)it * 16384 + 512);
    }
    #pragma unroll
    for (int j = 0; j < 4; ++j)
      #pragma unroll
      for (int k = 0; k < 8; ++k) {
        pacc[k] += (float)ka[j][k];
        pacc[8 + k] += (float)kb[j][k];
      }
  }
  float4 v0 = {pacc[0], pacc[1], pacc[2], pacc[3]};
  float4 v1 = {pacc[4], pacc[5], pacc[6], pacc[7]};
  float4 v2 = {pacc[8], pacc[9], pacc[10], pacc[11]};
  float4 v3 = {pacc[12], pacc[13], pacc[14], pacc[15]};
  *(float4*)&plds[w][lane * 8] = v0;
  *(float4*)&plds[w][lane * 8 + 4] = v1;
  *(float4*)&plds[w][512 + lane * 8] = v2;
  *(float4*)&plds[w][512 + lane * 8 + 4] = v3;
  __syncthreads();
  {
    int col = t;
    float sum = 0.f;
    #pragma unroll
    for (int i = 0; i < 16; ++i) sum += plds[i][col];
    dst[((size_t)b << 12) + (s << 10) + col] = (_Float16)sum;
  }
}

// ---------------------------------------------------------------- fused F
// block = (b, strip s of 256 rows); 16 waves, batch-4 rows per group.
// v = W1/(reduce(src)+eps); z = K v; u = W1/(z+eps); dst = strip K^T u (fp16).
// FINAL: z rows -> zb, G minmax -> mm; no dst.
template<int FINAL>
__global__ __launch_bounds__(1024, 4) void fused_kernel(
    const _Float16* __restrict__ Kh, const _Float16* __restrict__ src,
    _Float16* __restrict__ dst, float* __restrict__ zb,
    unsigned* __restrict__ mm) {
  int bid = blockIdx.x;
  int b = bid >> 2, s = bid & 3;
  int t = threadIdx.x, lane = t & 63, w = t >> 6;
  __shared__ float sv[1024];
  __shared__ float plds[16][1024];  // 64 KB
  __shared__ float red[32];
  {
    int col = t;
    const _Float16* sp = src + ((size_t)b << 12) + col;
    float y = (float)sp[0] + (float)sp[1024] + (float)sp[2048] + (float)sp[3072];
    sv[col] = W1 / (y + EPSV);
  }
  __syncthreads();
  float svr[16];
  {
    float4 s0 = *(const float4*)&sv[lane * 8];
    float4 s1 = *(const float4*)&sv[lane * 8 + 4];
    float4 s2 = *(const float4*)&sv[512 + lane * 8];
    float4 s3 = *(const float4*)&sv[512 + lane * 8 + 4];
    svr[0] = s0.x;  svr[1] = s0.y;  svr[2]  = s0.z;  svr[3]  = s0.w;
    svr[4] = s1.x;  svr[5] = s1.y;  svr[6]  = s1.z;  svr[7]  = s1.w;
    svr[8] = s2.x;  svr[9] = s2.y;  svr[10] = s2.z;  svr[11] = s2.w;
    svr[12] = s3.x; svr[13] = s3.y; svr[14] = s3.z;  svr[15] = s3.w;
  }
  float pacc[16];
  #pragma unroll
  for (int k = 0; k < 16; ++k) pacc[k] = 0.f;
  float gmn = 3.4e38f, gmx = 0.f;
  const _Float16* kp = Kh + ((size_t)b << 20) + (size_t)(s * 256 + w) * 1024 + lane * 8;
  #pragma unroll
  for (int g = 0; g < 4; ++g) {
    // batch 4 rows: loads together, dots together, butterflies interleaved
    h8 ka[4], kb[4];
    #pragma unroll
    for (int j = 0; j < 4; ++j) {
      int it = g * 4 + j;
      ka[j] = *(const h8*)(kp + (size_t)it * 16384);
      kb[j] = *(const h8*)(kp + (size_t)it * 16384 + 512);
    }
    float dot[4];
    #pragma unroll
    for (int j = 0; j < 4; ++j) {
      float d = 0.f;
      #pragma unroll
      for (int k = 0; k < 8; ++k)
        d += (float)ka[j][k] * svr[k] + (float)kb[j][k] * svr[8 + k];
      dot[j] = d;
    }
    #pragma unroll
    for (int off = 1; off < 64; off <<= 1) {
      #pragma unroll
      for (int j = 0; j < 4; ++j) dot[j] += __shfl_xor(dot[j], off, 64);
    }
    #pragma unroll
    for (int j = 0; j < 4; ++j) {
      int it = g * 4 + j;
      float u = W1 / (dot[j] + EPSV);
      if (FINAL) {
        if (lane == 0) zb[(b << 10) + s * 256 + w + it * 16] = dot[j];
        #pragma unroll
        for (int k = 0; k < 8; ++k) {
          float g0 = u * (float)ka[j][k] * svr[k];
          float g1 = u * (float)kb[j][k] * svr[8 + k];
          gmn = fminf(gmn, fminf(g0, g1)); gmx = fmaxf(gmx, fmaxf(g0, g1));
        }
      } else {
        #pragma unroll
        for (int k = 0; k < 8; ++k) {
          pacc[k] += (float)ka[j][k] * u;
          pacc[8 + k] += (float)kb[j][k] * u;
        }
      }
    }
  }
  if (!FINAL) {
    float4 v0 = {pacc[0], pacc[1], pacc[2], pacc[3]};
    float4 v1 = {pacc[4], pacc[5], pacc[6], pacc[7]};
    float4 v2 = {pacc[8], pacc[9], pacc[10], pacc[11]};
    float4 v3 = {pacc[12], pacc[13], pacc[14], pacc[15]};
    *(float4*)&plds[w][lane * 8] = v0;
    *(float4*)&plds[w][lane * 8 + 4] = v1;
    *(float4*)&plds[w][512 + lane * 8] = v2;
    *(float4*)&plds[w][512 + lane * 8 + 4] = v3;
    __syncthreads();
    {
      int col = t;
      float sum = 0.f;
      #pragma unroll
      for (int i = 0; i < 16; ++i) sum += plds[i][col];
      dst[((size_t)b << 12) + (s << 10) + col] = (_Float16)sum;
    }
  } else {
    #pragma unroll
    for (int off = 1; off < 64; off <<= 1) {
      gmn = fminf(gmn, __shfl_xor(gmn, off, 64));
      gmx = fmaxf(gmx, __shfl_xor(gmx, off, 64));
    }
    if (lane == 0) { red[w] = gmn; red[16 + w] = gmx; }
    __syncthreads();
    if (t == 0) {
      float m0 = red[0], m1 = red[16];
      #pragma unroll
      for (int i = 1; i < 16; ++i) { m0 = fminf(m0, red[i]); m1 = fmaxf(m1, red[16 + i]); }
      atomicMin(&mm[64 + b], __float_as_uint(m0));  // positive floats: uint order ok
      atomicMax(&mm[b],      __float_as_uint(m1));
    }
  }
}

// ---------------------------------------------------------------- fin
// out = ((G - gmin) / (gmax - gmin + eps)) * (-log K); v from src partials.
__global__ __launch_bounds__(256) void fin_kernel(
    const _Float16* __restrict__ Kh, const _Float16* __restrict__ src,
    const float* __restrict__ zb, const unsigned* __restrict__ mm,
    float* __restrict__ out) {
  int bid = blockIdx.x;
  int b = bid >> 4, rg = bid & 15;
  int t = threadIdx.x, lane = t & 63, w = t >> 6;
  __shared__ float sv[1024];
  #pragma unroll
  for (int p = 0; p < 4; ++p) {
    int col = (p << 8) + t;
    const _Float16* sp = src + ((size_t)b << 12) + col;
    float y = (float)sp[0] + (float)sp[1024] + (float)sp[2048] + (float)sp[3072];
    sv[col] = W1 / (y + EPSV);
  }
  __syncthreads();
  float svr[16];
  {
    float4 s0 = *(const float4*)&sv[lane * 8];
    float4 s1 = *(const float4*)&sv[lane * 8 + 4];
    float4 s2 = *(const float4*)&sv[512 + lane * 8];
    float4 s3 = *(const float4*)&sv[512 + lane * 8 + 4];
    svr[0] = s0.x;  svr[1] = s0.y;  svr[2]  = s0.z;  svr[3]  = s0.w;
    svr[4] = s1.x;  svr[5] = s1.y;  svr[6]  = s1.z;  svr[7]  = s1.w;
    svr[8] = s2.x;  svr[9] = s2.y;  svr[10] = s2.z;  svr[11] = s2.w;
    svr[12] = s3.x; svr[13] = s3.y; svr[14] = s3.z;  svr[15] = s3.w;
  }
  float gmx = __uint_as_float(mm[b]);
  float gmn = __uint_as_float(mm[64 + b]);
  float scale = 1.0f / (gmx - gmn + EPSV);
  const _Float16* kp = Kh + ((size_t)b << 20) + (size_t)(rg * 64 + w) * 1024 + lane * 8;
  float* op = out + ((size_t)b << 20) + (size_t)(rg * 64 + w) * 1024 + lane * 8;
  for (int it = 0; it < 16; ++it) {
    int r = rg * 64 + w + it * 4;
    float u = W1 / (zb[b * 1024 + r] + EPSV);
    h8 k0 = *(const h8*)(kp + (size_t)it * 4096);
    h8 k1 = *(const h8*)(kp + (size_t)it * 4096 + 512);
    float o[16];
    #pragma unroll
    for (int k = 0; k < 8; ++k) {
      float kfa = (float)k0[k];
      float kfb = (float)k1[k];
      float ga = u * kfa * svr[k];
      float gb = u * kfb * svr[8 + k];
      o[k]     = (ga - gmn) * scale * (-__logf(kfa));
      o[8 + k] = (gb - gmn) * scale * (-__logf(kfb));
    }
    float4 o0 = {o[0], o[1], o[2], o[3]};
    float4 o1 = {o[4], o[5], o[6], o[7]};
    float4 o2 = {o[8], o[9], o[10], o[11]};
    float4 o3 = {o[12], o[13], o[14], o[15]};
    *(float4*)(op + (size_t)it * 4096) = o0;
    *(float4*)(op + (size_t)it * 4096 + 4) = o1;
    *(float4*)(op + (size_t)it * 4096 + 512) = o2;
    *(float4*)(op + (size_t)it * 4096 + 516) = o3;
  }
}

// ---------------------------------------------------------------- launch
extern "C" void kernel_launch(void* const* d_in, const int* in_sizes, int n_in,
                              void* d_out, int out_size, void* d_ws, size_t ws_size,
                              hipStream_t stream) {
  const float* x1 = (const float*)d_in[0];
  const float* x2 = (const float*)d_in[1];
  float* out = (float*)d_out;
  char* ws = (char*)d_ws;

  // ws layout (bytes) — identical to round-3 proven layout
  _Float16* Kh    = (_Float16*)(ws);                      // 134217728
  float*    n1    = (float*)(ws + 134217728ULL);          // 262144 (reused as zb)
  float*    zb    = (float*)(ws + 134217728ULL);
  float*    n2    = (float*)(ws + 134479872ULL);          // 262144
  _Float16* pA    = (_Float16*)(ws + 134742016ULL);       // 524288
  _Float16* pB    = (_Float16*)(ws + 135266304ULL);       // 524288
  unsigned* mm    = (unsigned*)(ws + 135790592ULL);       // 512
  const size_t WS_NEED = 135791104ULL;                    // <= proven 136053248

  if (ws_size < WS_NEED) {
    float val = 100.0f + (float)(ws_size >> 20);
    diag_kernel<<<2048, 256, 0, stream>>>(out, val, out_size);
    return;
  }

  prep_kernel<<<32768, 256, 0, stream>>>(x1, x2, n1, n2, mm);
  gemm_kernel<<<4096, 256, 0, stream>>>(x1, x2, n1, n2, Kh);
  ktu0_kernel<<<256, 1024, 0, stream>>>(Kh, pA);
  for (int k = 1; k <= 9; ++k) {
    _Float16* src = (k & 1) ? pA : pB;
    _Float16* dst = (k & 1) ? pB : pA;
    fused_kernel<0><<<256, 1024, 0, stream>>>(Kh, src, dst, zb, mm);
  }
  // k=10 FINAL: src = p9 (pB); writes zb + minmax only
  fused_kernel<1><<<256, 1024, 0, stream>>>(Kh, pB, pA, zb, mm);
  fin_kernel<<<1024, 256, 0, stream>>>(Kh, pB, zb, mm, out);
}

// Round 7
// 506.975 us; speedup vs baseline: 3.1971x; 3.1971x over previous
//
#include <hip/hip_runtime.h>
#include <hip/hip_bf16.h>
#include <hip/hip_fp8.h>

// Sinkhorn on MI355X. B=64, L=1024, D=256.
// K stored as fp8-e4m3 plane K8 (64MB) + fp8 relative-residual plane R8 (64MB):
//   K_rec = dec(K8) * (1 + dec(R8))  ~= K_fp16 accuracy (0.2%).
// prep -> gemm (cos -> K8+R8) -> ktu0 (colsums, fp8)
//   -> passes 1..8 fused fp8 (64MB/pass), 9..10 fused reconstructed (128MB)
//   -> fin (out = minmax-norm(u*K_rec*v^T) * (-log K_rec))
// Loop shape identical to proven R3 (1 row/iter, unroll 2, 512thr, 256 blocks).
// WS_NEED = 135791104 <= proven-available 136053248.

#define EPSV 1e-12f
#define W1 0.0009765625f   // 1/1024

typedef short  short8 __attribute__((ext_vector_type(8)));
typedef float  f32x4  __attribute__((ext_vector_type(4)));
typedef float  f32x2v __attribute__((ext_vector_type(2)));

// ---- fp8 e4m3 helpers (HW builtins, HIP-type fallback) ----
__device__ __forceinline__ unsigned char enc1(float x) {
#if __has_builtin(__builtin_amdgcn_cvt_pk_fp8_f32)
  int v = __builtin_amdgcn_cvt_pk_fp8_f32(x, x, 0, false);
  return (unsigned char)(v & 0xff);
#else
  __hip_fp8_e4m3 q(x); return (unsigned char)q.__x;
#endif
}
__device__ __forceinline__ float dec1(unsigned char b) {
#if __has_builtin(__builtin_amdgcn_cvt_f32_fp8)
  return __builtin_amdgcn_cvt_f32_fp8((int)b, 0);
#else
  __hip_fp8_e4m3 q; q.__x = (__hip_fp8_storage_t)b; return (float)q;
#endif
}
__device__ __forceinline__ void decode16(uint4 d, float* f) {
#if __has_builtin(__builtin_amdgcn_cvt_pk_f32_fp8)
  f32x2v p;
  p = __builtin_amdgcn_cvt_pk_f32_fp8((int)d.x, false); f[0]=p[0];  f[1]=p[1];
  p = __builtin_amdgcn_cvt_pk_f32_fp8((int)d.x, true);  f[2]=p[0];  f[3]=p[1];
  p = __builtin_amdgcn_cvt_pk_f32_fp8((int)d.y, false); f[4]=p[0];  f[5]=p[1];
  p = __builtin_amdgcn_cvt_pk_f32_fp8((int)d.y, true);  f[6]=p[0];  f[7]=p[1];
  p = __builtin_amdgcn_cvt_pk_f32_fp8((int)d.z, false); f[8]=p[0];  f[9]=p[1];
  p = __builtin_amdgcn_cvt_pk_f32_fp8((int)d.z, true);  f[10]=p[0]; f[11]=p[1];
  p = __builtin_amdgcn_cvt_pk_f32_fp8((int)d.w, false); f[12]=p[0]; f[13]=p[1];
  p = __builtin_amdgcn_cvt_pk_f32_fp8((int)d.w, true);  f[14]=p[0]; f[15]=p[1];
#else
  unsigned v[4] = {d.x, d.y, d.z, d.w};
  #pragma unroll
  for (int i = 0; i < 16; ++i)
    f[i] = dec1((unsigned char)((v[i >> 2] >> ((i & 3) * 8)) & 0xff));
#endif
}

// load 8 consecutive floats, convert to 8 bf16 (hw v_cvt_pk_bf16_f32)
__device__ __forceinline__ short8 ld_cvt8(const float* p) {
  float4 f0 = *(const float4*)p;
  float4 f1 = *(const float4*)(p + 4);
  float2 p0; p0.x = f0.x; p0.y = f0.y;
  float2 p1; p1.x = f0.z; p1.y = f0.w;
  float2 p2; p2.x = f1.x; p2.y = f1.y;
  float2 p3; p3.x = f1.z; p3.y = f1.w;
  __hip_bfloat162 h0 = __float22bfloat162_rn(p0);
  __hip_bfloat162 h1 = __float22bfloat162_rn(p1);
  __hip_bfloat162 h2_ = __float22bfloat162_rn(p2);
  __hip_bfloat162 h3 = __float22bfloat162_rn(p3);
  short2 a = *(short2*)&h0, b = *(short2*)&h1, c = *(short2*)&h2_, d = *(short2*)&h3;
  short8 r;
  r[0] = a.x; r[1] = a.y; r[2] = b.x; r[3] = b.y;
  r[4] = c.x; r[5] = c.y; r[6] = d.x; r[7] = d.y;
  return r;
}

// ---------------------------------------------------------------- diag
__global__ __launch_bounds__(256) void diag_kernel(float* __restrict__ out,
                                                   float val, int n) {
  int stride = gridDim.x * 256;
  for (int i = blockIdx.x * 256 + threadIdx.x; i < n; i += stride) out[i] = val;
}

// ---------------------------------------------------------------- prep
__global__ __launch_bounds__(256) void prep_kernel(
    const float* __restrict__ x1, const float* __restrict__ x2,
    float* __restrict__ n1, float* __restrict__ n2,
    unsigned* __restrict__ mm) {
  int t = threadIdx.x, bid = blockIdx.x;
  if (bid == 0 && t < 128) mm[t] = (t < 64) ? 0u : 0x7f800000u;
  int row = bid * 4 + (t >> 6);
  int lane = t & 63;
  const float* xp; float* np_;
  int r = row;
  if (row < 65536) { xp = x1; np_ = n1; }
  else { r = row - 65536; xp = x2; np_ = n2; }
  float4 v = ((const float4*)(xp + (size_t)r * 256))[lane];
  float s = v.x * v.x + v.y * v.y + v.z * v.z + v.w * v.w;
  #pragma unroll
  for (int off = 1; off < 64; off <<= 1) s += __shfl_xor(s, off, 64);
  if (lane == 0) np_[r] = sqrtf(s);
}

// ---------------------------------------------------------------- gemm
// 128x128 tile, BK=64, 4 waves (2x2 of 64x64), mfma_f32_16x16x32_bf16.
// Epilogue: K=exp(cos-1) -> fp8 K8 + fp8 residual R8 (K_rec = k8*(1+r8)).
__global__ __launch_bounds__(256) void gemm_kernel(
    const float* __restrict__ x1, const float* __restrict__ x2,
    const float* __restrict__ n1, const float* __restrict__ n2,
    unsigned char* __restrict__ K8g, unsigned char* __restrict__ R8g) {
  __shared__ __align__(16) unsigned short smem[2 * 128 * 64];  // 32 KB
  unsigned short* As = smem;
  unsigned short* Bs = smem + 128 * 64;
  int bid = blockIdx.x;
  int b = bid >> 6, tile = bid & 63;
  int ti = (tile >> 3) << 7, tj = (tile & 7) << 7;
  int t = threadIdx.x, lane = t & 63, wave = t >> 6;
  int wr = (wave >> 1) << 6, wc = (wave & 1) << 6;
  const float* Ag = x1 + ((size_t)(b * 1024 + ti)) * 256;
  const float* Bg = x2 + ((size_t)(b * 1024 + tj)) * 256;

  f32x4 acc[4][4];
  f32x4 zero = {0.f, 0.f, 0.f, 0.f};
  #pragma unroll
  for (int m = 0; m < 4; ++m)
    #pragma unroll
    for (int n = 0; n < 4; ++n) acc[m][n] = zero;

  short8 ra[4], rb[4];
  #pragma unroll
  for (int c = 0; c < 4; ++c) {
    int ch = t + (c << 8); int row = ch >> 3, kg = ch & 7;
    ra[c] = ld_cvt8(Ag + row * 256 + kg * 8);
    rb[c] = ld_cvt8(Bg + row * 256 + kg * 8);
  }

  for (int k0 = 0; k0 < 4; ++k0) {
    __syncthreads();
    #pragma unroll
    for (int c = 0; c < 4; ++c) {
      int ch = t + (c << 8); int row = ch >> 3, kg = ch & 7;
      int kgs = kg ^ (row & 7);
      *(short8*)(As + row * 64 + kgs * 8) = ra[c];
      *(short8*)(Bs + row * 64 + kgs * 8) = rb[c];
    }
    __syncthreads();
    if (k0 < 3) {
      #pragma unroll
      for (int c = 0; c < 4; ++c) {
        int ch = t + (c << 8); int row = ch >> 3, kg = ch & 7;
        ra[c] = ld_cvt8(Ag + row * 256 + (k0 + 1) * 64 + kg * 8);
        rb[c] = ld_cvt8(Bg + row * 256 + (k0 + 1) * 64 + kg * 8);
      }
    }
    #pragma unroll
    for (int ks = 0; ks < 2; ++ks) {
      short8 af[4], bfr[4];
      #pragma unroll
      for (int m = 0; m < 4; ++m) {
        int row = wr + m * 16 + (lane & 15);
        int c16 = (ks << 2) + (lane >> 4);
        af[m] = *(const short8*)(As + row * 64 + ((c16 ^ (row & 7)) << 3));
      }
      #pragma unroll
      for (int n = 0; n < 4; ++n) {
        int row = wc + n * 16 + (lane & 15);
        int c16 = (ks << 2) + (lane >> 4);
        bfr[n] = *(const short8*)(Bs + row * 64 + ((c16 ^ (row & 7)) << 3));
      }
      #pragma unroll
      for (int m = 0; m < 4; ++m)
        #pragma unroll
        for (int n = 0; n < 4; ++n)
          acc[m][n] = __builtin_amdgcn_mfma_f32_16x16x32_bf16(af[m], bfr[n], acc[m][n], 0, 0, 0);
    }
  }
  __syncthreads();

  // epilogue: cos -> k -> (K8, R8) byte planes in LDS, then coalesced stores
  unsigned char* CtK = (unsigned char*)smem;           // 16 KB
  unsigned char* CtR = ((unsigned char*)smem) + 16384; // 16 KB
  float a1v[4][4], b2v[4];
  #pragma unroll
  for (int m = 0; m < 4; ++m)
    #pragma unroll
    for (int q = 0; q < 4; ++q)
      a1v[m][q] = n1[(size_t)b * 1024 + ti + wr + m * 16 + ((lane >> 4) << 2) + q];
  #pragma unroll
  for (int n = 0; n < 4; ++n)
    b2v[n] = n2[(size_t)b * 1024 + tj + wc + n * 16 + (lane & 15)];
  #pragma unroll
  for (int m = 0; m < 4; ++m)
    #pragma unroll
    for (int n = 0; n < 4; ++n)
      #pragma unroll
      for (int q = 0; q < 4; ++q) {
        int rl = wr + m * 16 + ((lane >> 4) << 2) + q;
        int cl = wc + n * 16 + (lane & 15);
        float cosv = acc[m][n][q] / (a1v[m][q] * b2v[n] + EPSV);
        float kv = __expf(cosv - 1.0f);
        unsigned char q8 = enc1(kv);
        float kd = dec1(q8);
        float rr = kv / kd - 1.0f;
        CtK[rl * 128 + cl] = q8;
        CtR[rl * 128 + cl] = enc1(rr);
      }
  __syncthreads();
  size_t kbase = ((size_t)b << 20);
  #pragma unroll
  for (int i = 0; i < 4; ++i) {
    int idx = t + (i << 8);          // 1024 chunks of 16B per plane
    int row = idx >> 3, seg = idx & 7;
    size_t off = kbase + (size_t)(ti + row) * 1024 + tj + seg * 16;
    *(uint4*)(K8g + off) = ((const uint4*)CtK)[idx];
    *(uint4*)(R8g + off) = ((const uint4*)CtR)[idx];
  }
}

// ---------------------------------------------------------------- ktu0
// p0 = column sums of K8 per 256-row strip (u0=1). R3 loop shape, fp8 loads.
__global__ __launch_bounds__(512) void ktu0_kernel(
    const unsigned char* __restrict__ K8, _Float16* __restrict__ dst) {
  int bid = blockIdx.x;
  int b = bid >> 2, s = bid & 3;
  int t = threadIdx.x, lane = t & 63, w = t >> 6;
  __shared__ float plds[8][1024];  // 32 KB
  float pacc[16];
  #pragma unroll
  for (int k = 0; k < 16; ++k) pacc[k] = 0.f;
  const unsigned char* kp = K8 + ((size_t)b << 20) + (size_t)(s * 256 + w) * 1024 + lane * 16;
  #pragma unroll 2
  for (int it = 0; it < 32; ++it) {
    uint4 dk = *(const uint4*)(kp + (size_t)it * 8192);
    float kf[16];
    decode16(dk, kf);
    #pragma unroll
    for (int k = 0; k < 16; ++k) pacc[k] += kf[k];
  }
  *(float4*)&plds[w][lane * 16]      = *(float4*)&pacc[0];
  *(float4*)&plds[w][lane * 16 + 4]  = *(float4*)&pacc[4];
  *(float4*)&plds[w][lane * 16 + 8]  = *(float4*)&pacc[8];
  *(float4*)&plds[w][lane * 16 + 12] = *(float4*)&pacc[12];
  __syncthreads();
  #pragma unroll
  for (int p = 0; p < 2; ++p) {
    int col = (p << 9) + t;
    float sum = plds[0][col] + plds[1][col] + plds[2][col] + plds[3][col]
              + plds[4][col] + plds[5][col] + plds[6][col] + plds[7][col];
    dst[((size_t)b << 12) + (s << 10) + col] = (_Float16)sum;
  }
}

// ---------------------------------------------------------------- fused F
// R3 loop shape. RECON: reconstruct K_rec = k8*(1+r8). FINAL: z+minmax only.
template<int RECON, int FINAL>
__global__ __launch_bounds__(512) void fused_kernel(
    const unsigned char* __restrict__ K8, const unsigned char* __restrict__ R8,
    const _Float16* __restrict__ src, _Float16* __restrict__ dst,
    float* __restrict__ zb, unsigned* __restrict__ mm) {
  int bid = blockIdx.x;
  int b = bid >> 2, s = bid & 3;
  int t = threadIdx.x, lane = t & 63, w = t >> 6;
  __shared__ float sv[1024];
  __shared__ float plds[8][1024];  // 32 KB
  __shared__ float red[16];
  #pragma unroll
  for (int p = 0; p < 2; ++p) {
    int col = (p << 9) + t;
    const _Float16* sp = src + ((size_t)b << 12) + col;
    float y = (float)sp[0] + (float)sp[1024] + (float)sp[2048] + (float)sp[3072];
    sv[col] = W1 / (y + EPSV);
  }
  __syncthreads();
  float svr[16];
  {
    float4 s0 = *(const float4*)&sv[lane * 16];
    float4 s1 = *(const float4*)&sv[lane * 16 + 4];
    float4 s2 = *(const float4*)&sv[lane * 16 + 8];
    float4 s3 = *(const float4*)&sv[lane * 16 + 12];
    svr[0] = s0.x;  svr[1] = s0.y;  svr[2]  = s0.z;  svr[3]  = s0.w;
    svr[4] = s1.x;  svr[5] = s1.y;  svr[6]  = s1.z;  svr[7]  = s1.w;
    svr[8] = s2.x;  svr[9] = s2.y;  svr[10] = s2.z;  svr[11] = s2.w;
    svr[12] = s3.x; svr[13] = s3.y; svr[14] = s3.z;  svr[15] = s3.w;
  }
  float pacc[16];
  #pragma unroll
  for (int k = 0; k < 16; ++k) pacc[k] = 0.f;
  float gmn = 3.4e38f, gmx = 0.f;
  const unsigned char* kp = K8 + ((size_t)b << 20) + (size_t)(s * 256 + w) * 1024 + lane * 16;
  const unsigned char* rp = R8 + ((size_t)b << 20) + (size_t)(s * 256 + w) * 1024 + lane * 16;
  #pragma unroll 2
  for (int it = 0; it < 32; ++it) {
    uint4 dk = *(const uint4*)(kp + (size_t)it * 8192);
    float kf[16];
    decode16(dk, kf);
    if (RECON) {
      uint4 dr = *(const uint4*)(rp + (size_t)it * 8192);
      float rf[16];
      decode16(dr, rf);
      #pragma unroll
      for (int k = 0; k < 16; ++k) kf[k] *= (1.0f + rf[k]);
    }
    float dot = 0.f;
    #pragma unroll
    for (int k = 0; k < 16; ++k) dot += kf[k] * svr[k];
    #pragma unroll
    for (int off = 1; off < 64; off <<= 1) dot += __shfl_xor(dot, off, 64);
    float u = W1 / (dot + EPSV);
    if (FINAL) {
      if (lane == 0) zb[(b << 10) + s * 256 + w + it * 8] = dot;
      #pragma unroll
      for (int k = 0; k < 16; ++k) {
        float g = u * kf[k] * svr[k];
        gmn = fminf(gmn, g); gmx = fmaxf(gmx, g);
      }
    } else {
      #pragma unroll
      for (int k = 0; k < 16; ++k) pacc[k] += kf[k] * u;
    }
  }
  if (!FINAL) {
    *(float4*)&plds[w][lane * 16]      = *(float4*)&pacc[0];
    *(float4*)&plds[w][lane * 16 + 4]  = *(float4*)&pacc[4];
    *(float4*)&plds[w][lane * 16 + 8]  = *(float4*)&pacc[8];
    *(float4*)&plds[w][lane * 16 + 12] = *(float4*)&pacc[12];
    __syncthreads();
    #pragma unroll
    for (int p = 0; p < 2; ++p) {
      int col = (p << 9) + t;
      float sum = plds[0][col] + plds[1][col] + plds[2][col] + plds[3][col]
                + plds[4][col] + plds[5][col] + plds[6][col] + plds[7][col];
      dst[((size_t)b << 12) + (s << 10) + col] = (_Float16)sum;
    }
  } else {
    #pragma unroll
    for (int off = 1; off < 64; off <<= 1) {
      gmn = fminf(gmn, __shfl_xor(gmn, off, 64));
      gmx = fmaxf(gmx, __shfl_xor(gmx, off, 64));
    }
    if (lane == 0) { red[w] = gmn; red[8 + w] = gmx; }
    __syncthreads();
    if (t == 0) {
      float m0 = red[0], m1 = red[8];
      #pragma unroll
      for (int i = 1; i < 8; ++i) { m0 = fminf(m0, red[i]); m1 = fmaxf(m1, red[8 + i]); }
      atomicMin(&mm[64 + b], __float_as_uint(m0));  // positive floats: uint order ok
      atomicMax(&mm[b],      __float_as_uint(m1));
    }
  }
}

// ---------------------------------------------------------------- fin
// out = ((G - gmin)/(gmax - gmin + eps)) * (-log K_rec)
__global__ __launch_bounds__(256) void fin_kernel(
    const unsigned char* __restrict__ K8, const unsigned char* __restrict__ R8,
    const _Float16* __restrict__ src, const float* __restrict__ zb,
    const unsigned* __restrict__ mm, float* __restrict__ out) {
  int bid = blockIdx.x;
  int b = bid >> 4, rg = bid & 15;
  int t = threadIdx.x, lane = t & 63, w = t >> 6;
  __shared__ float sv[1024];
  #pragma unroll
  for (int p = 0; p < 4; ++p) {
    int col = (p << 8) + t;
    const _Float16* sp = src + ((size_t)b << 12) + col;
    float y = (float)sp[0] + (float)sp[1024] + (float)sp[2048] + (float)sp[3072];
    sv[col] = W1 / (y + EPSV);
  }
  __syncthreads();
  float svr[16];
  {
    float4 s0 = *(const float4*)&sv[lane * 16];
    float4 s1 = *(const float4*)&sv[lane * 16 + 4];
    float4 s2 = *(const float4*)&sv[lane * 16 + 8];
    float4 s3 = *(const float4*)&sv[lane * 16 + 12];
    svr[0] = s0.x;  svr[1] = s0.y;  svr[2]  = s0.z;  svr[3]  = s0.w;
    svr[4] = s1.x;  svr[5] = s1.y;  svr[6]  = s1.z;  svr[7]  = s1.w;
    svr[8] = s2.x;  svr[9] = s2.y;  svr[10] = s2.z;  svr[11] = s2.w;
    svr[12] = s3.x; svr[13] = s3.y; svr[14] = s3.z;  svr[15] = s3.w;
  }
  float gmx = __uint_as_float(mm[b]);
  float gmn = __uint_as_float(mm[64 + b]);
  float scale = 1.0f / (gmx - gmn + EPSV);
  const unsigned char* kp = K8 + ((size_t)b << 20) + (size_t)(rg * 64 + w) * 1024 + lane * 16;
  const unsigned char* rp = R8 + ((size_t)b << 20) + (size_t)(rg * 64 + w) * 1024 + lane * 16;
  float* op = out + ((size_t)b << 20) + (size_t)(rg * 64 + w) * 1024 + lane * 16;
  for (int it = 0; it < 16; ++it) {
    int r = rg * 64 + w + it * 4;
    float u = W1 / (zb[b * 1024 + r] + EPSV);
    uint4 dk = *(const uint4*)(kp + (size_t)it * 4096);
    uint4 dr = *(const uint4*)(rp + (size_t)it * 4096);
    float kf[16], rf[16], o[16];
    decode16(dk, kf);
    decode16(dr, rf);
    #pragma unroll
    for (int k = 0; k < 16; ++k) {
      float krec = kf[k] * (1.0f + rf[k]);
      float g = u * krec * svr[k];
      o[k] = (g - gmn) * scale * (-__logf(krec));
    }
    *(float4*)(op + (size_t)it * 4096)      = *(float4*)&o[0];
    *(float4*)(op + (size_t)it * 4096 + 4)  = *(float4*)&o[4];
    *(float4*)(op + (size_t)it * 4096 + 8)  = *(float4*)&o[8];
    *(float4*)(op + (size_t)it * 4096 + 12) = *(float4*)&o[12];
  }
}

// ---------------------------------------------------------------- launch
extern "C" void kernel_launch(void* const* d_in, const int* in_sizes, int n_in,
                              void* d_out, int out_size, void* d_ws, size_t ws_size,
                              hipStream_t stream) {
  const float* x1 = (const float*)d_in[0];
  const float* x2 = (const float*)d_in[1];
  float* out = (float*)d_out;
  char* ws = (char*)d_ws;

  // ws layout (bytes)
  unsigned char* K8g = (unsigned char*)ws;                 // 67108864
  unsigned char* R8g = (unsigned char*)(ws + 67108864ULL); // 67108864
  float*    n1 = (float*)(ws + 134217728ULL);              // 262144 (reused as zb)
  float*    zb = (float*)(ws + 134217728ULL);
  float*    n2 = (float*)(ws + 134479872ULL);              // 262144
  _Float16* pA = (_Float16*)(ws + 134742016ULL);           // 524288
  _Float16* pB = (_Float16*)(ws + 135266304ULL);           // 524288
  unsigned* mm = (unsigned*)(ws + 135790592ULL);           // 512
  const size_t WS_NEED = 135791104ULL;                     // <= proven 136053248

  if (ws_size < WS_NEED) {
    float val = 100.0f + (float)(ws_size >> 20);
    diag_kernel<<<2048, 256, 0, stream>>>(out, val, out_size);
    return;
  }

  prep_kernel<<<32768, 256, 0, stream>>>(x1, x2, n1, n2, mm);
  gemm_kernel<<<4096, 256, 0, stream>>>(x1, x2, n1, n2, K8g, R8g);
  ktu0_kernel<<<256, 512, 0, stream>>>(K8g, pA);
  for (int k = 1; k <= 8; ++k) {
    _Float16* src = (k & 1) ? pA : pB;
    _Float16* dst = (k & 1) ? pB : pA;
    fused_kernel<0, 0><<<256, 512, 0, stream>>>(K8g, R8g, src, dst, zb, mm);
  }
  // k=9: reconstructed K for accuracy re-convergence
  fused_kernel<1, 0><<<256, 512, 0, stream>>>(K8g, R8g, pA, pB, zb, mm);
  // k=10 FINAL: reconstructed K; writes zb + minmax only
  fused_kernel<1, 1><<<256, 512, 0, stream>>>(K8g, R8g, pB, pA, zb, mm);
  fin_kernel<<<1024, 256, 0, stream>>>(K8g, R8g, pB, zb, mm, out);
}

// Round 8
// 453.437 us; speedup vs baseline: 3.5745x; 1.1181x over previous
//
#include <hip/hip_runtime.h>
#include <hip/hip_bf16.h>
#include <hip/hip_fp8.h>

// Sinkhorn on MI355X. B=64, L=1024, D=256.
// K stored as fp8-e4m3 plane K8 (64MB) + fp8 relative-residual plane R8 (64MB):
//   K_rec = dec(K8) * (1 + dec(R8))  ~= fp16 accuracy (0.2%).
// prep -> gemm (cos -> K8+R8) -> ktu0 (colsums, fp8)
//   -> passes 1..8 fused fp8, 9..10 fused reconstructed
//   -> fin (out = minmax-norm(u*K_rec*v^T) * (-log K_rec))
// R8 change: fused passes batch-2 rows + SW prefetch (attack ~2000cy/row
// serial chain: load-wait + dot + 6-level butterfly; ILP=2).
// WS_NEED = 135791104 <= proven-available 136053248.

#define EPSV 1e-12f
#define W1 0.0009765625f   // 1/1024

typedef short  short8 __attribute__((ext_vector_type(8)));
typedef float  f32x4  __attribute__((ext_vector_type(4)));
typedef float  f32x2v __attribute__((ext_vector_type(2)));

// ---- fp8 e4m3 helpers (HW builtins, HIP-type fallback) ----
__device__ __forceinline__ unsigned char enc1(float x) {
#if __has_builtin(__builtin_amdgcn_cvt_pk_fp8_f32)
  int v = __builtin_amdgcn_cvt_pk_fp8_f32(x, x, 0, false);
  return (unsigned char)(v & 0xff);
#else
  __hip_fp8_e4m3 q(x); return (unsigned char)q.__x;
#endif
}
__device__ __forceinline__ float dec1(unsigned char b) {
#if __has_builtin(__builtin_amdgcn_cvt_f32_fp8)
  return __builtin_amdgcn_cvt_f32_fp8((int)b, 0);
#else
  __hip_fp8_e4m3 q; q.__x = (__hip_fp8_storage_t)b; return (float)q;
#endif
}
__device__ __forceinline__ void decode16(uint4 d, float* f) {
#if __has_builtin(__builtin_amdgcn_cvt_pk_f32_fp8)
  f32x2v p;
  p = __builtin_amdgcn_cvt_pk_f32_fp8((int)d.x, false); f[0]=p[0];  f[1]=p[1];
  p = __builtin_amdgcn_cvt_pk_f32_fp8((int)d.x, true);  f[2]=p[0];  f[3]=p[1];
  p = __builtin_amdgcn_cvt_pk_f32_fp8((int)d.y, false); f[4]=p[0];  f[5]=p[1];
  p = __builtin_amdgcn_cvt_pk_f32_fp8((int)d.y, true);  f[6]=p[0];  f[7]=p[1];
  p = __builtin_amdgcn_cvt_pk_f32_fp8((int)d.z, false); f[8]=p[0];  f[9]=p[1];
  p = __builtin_amdgcn_cvt_pk_f32_fp8((int)d.z, true);  f[10]=p[0]; f[11]=p[1];
  p = __builtin_amdgcn_cvt_pk_f32_fp8((int)d.w, false); f[12]=p[0]; f[13]=p[1];
  p = __builtin_amdgcn_cvt_pk_f32_fp8((int)d.w, true);  f[14]=p[0]; f[15]=p[1];
#else
  unsigned v[4] = {d.x, d.y, d.z, d.w};
  #pragma unroll
  for (int i = 0; i < 16; ++i)
    f[i] = dec1((unsigned char)((v[i >> 2] >> ((i & 3) * 8)) & 0xff));
#endif
}

// load 8 consecutive floats, convert to 8 bf16 (hw v_cvt_pk_bf16_f32)
__device__ __forceinline__ short8 ld_cvt8(const float* p) {
  float4 f0 = *(const float4*)p;
  float4 f1 = *(const float4*)(p + 4);
  float2 p0; p0.x = f0.x; p0.y = f0.y;
  float2 p1; p1.x = f0.z; p1.y = f0.w;
  float2 p2; p2.x = f1.x; p2.y = f1.y;
  float2 p3; p3.x = f1.z; p3.y = f1.w;
  __hip_bfloat162 h0 = __float22bfloat162_rn(p0);
  __hip_bfloat162 h1 = __float22bfloat162_rn(p1);
  __hip_bfloat162 h2_ = __float22bfloat162_rn(p2);
  __hip_bfloat162 h3 = __float22bfloat162_rn(p3);
  short2 a = *(short2*)&h0, b = *(short2*)&h1, c = *(short2*)&h2_, d = *(short2*)&h3;
  short8 r;
  r[0] = a.x; r[1] = a.y; r[2] = b.x; r[3] = b.y;
  r[4] = c.x; r[5] = c.y; r[6] = d.x; r[7] = d.y;
  return r;
}

// ---------------------------------------------------------------- diag
__global__ __launch_bounds__(256) void diag_kernel(float* __restrict__ out,
                                                   float val, int n) {
  int stride = gridDim.x * 256;
  for (int i = blockIdx.x * 256 + threadIdx.x; i < n; i += stride) out[i] = val;
}

// ---------------------------------------------------------------- prep
__global__ __launch_bounds__(256) void prep_kernel(
    const float* __restrict__ x1, const float* __restrict__ x2,
    float* __restrict__ n1, float* __restrict__ n2,
    unsigned* __restrict__ mm) {
  int t = threadIdx.x, bid = blockIdx.x;
  if (bid == 0 && t < 128) mm[t] = (t < 64) ? 0u : 0x7f800000u;
  int row = bid * 4 + (t >> 6);
  int lane = t & 63;
  const float* xp; float* np_;
  int r = row;
  if (row < 65536) { xp = x1; np_ = n1; }
  else { r = row - 65536; xp = x2; np_ = n2; }
  float4 v = ((const float4*)(xp + (size_t)r * 256))[lane];
  float s = v.x * v.x + v.y * v.y + v.z * v.z + v.w * v.w;
  #pragma unroll
  for (int off = 1; off < 64; off <<= 1) s += __shfl_xor(s, off, 64);
  if (lane == 0) np_[r] = sqrtf(s);
}

// ---------------------------------------------------------------- gemm
// 128x128 tile, BK=64, 4 waves (2x2 of 64x64), mfma_f32_16x16x32_bf16.
// Epilogue: K=exp(cos-1) -> fp8 K8 + fp8 residual R8 (K_rec = k8*(1+r8)).
__global__ __launch_bounds__(256) void gemm_kernel(
    const float* __restrict__ x1, const float* __restrict__ x2,
    const float* __restrict__ n1, const float* __restrict__ n2,
    unsigned char* __restrict__ K8g, unsigned char* __restrict__ R8g) {
  __shared__ __align__(16) unsigned short smem[2 * 128 * 64];  // 32 KB
  unsigned short* As = smem;
  unsigned short* Bs = smem + 128 * 64;
  int bid = blockIdx.x;
  int b = bid >> 6, tile = bid & 63;
  int ti = (tile >> 3) << 7, tj = (tile & 7) << 7;
  int t = threadIdx.x, lane = t & 63, wave = t >> 6;
  int wr = (wave >> 1) << 6, wc = (wave & 1) << 6;
  const float* Ag = x1 + ((size_t)(b * 1024 + ti)) * 256;
  const float* Bg = x2 + ((size_t)(b * 1024 + tj)) * 256;

  f32x4 acc[4][4];
  f32x4 zero = {0.f, 0.f, 0.f, 0.f};
  #pragma unroll
  for (int m = 0; m < 4; ++m)
    #pragma unroll
    for (int n = 0; n < 4; ++n) acc[m][n] = zero;

  short8 ra[4], rb[4];
  #pragma unroll
  for (int c = 0; c < 4; ++c) {
    int ch = t + (c << 8); int row = ch >> 3, kg = ch & 7;
    ra[c] = ld_cvt8(Ag + row * 256 + kg * 8);
    rb[c] = ld_cvt8(Bg + row * 256 + kg * 8);
  }

  for (int k0 = 0; k0 < 4; ++k0) {
    __syncthreads();
    #pragma unroll
    for (int c = 0; c < 4; ++c) {
      int ch = t + (c << 8); int row = ch >> 3, kg = ch & 7;
      int kgs = kg ^ (row & 7);
      *(short8*)(As + row * 64 + kgs * 8) = ra[c];
      *(short8*)(Bs + row * 64 + kgs * 8) = rb[c];
    }
    __syncthreads();
    if (k0 < 3) {
      #pragma unroll
      for (int c = 0; c < 4; ++c) {
        int ch = t + (c << 8); int row = ch >> 3, kg = ch & 7;
        ra[c] = ld_cvt8(Ag + row * 256 + (k0 + 1) * 64 + kg * 8);
        rb[c] = ld_cvt8(Bg + row * 256 + (k0 + 1) * 64 + kg * 8);
      }
    }
    #pragma unroll
    for (int ks = 0; ks < 2; ++ks) {
      short8 af[4], bfr[4];
      #pragma unroll
      for (int m = 0; m < 4; ++m) {
        int row = wr + m * 16 + (lane & 15);
        int c16 = (ks << 2) + (lane >> 4);
        af[m] = *(const short8*)(As + row * 64 + ((c16 ^ (row & 7)) << 3));
      }
      #pragma unroll
      for (int n = 0; n < 4; ++n) {
        int row = wc + n * 16 + (lane & 15);
        int c16 = (ks << 2) + (lane >> 4);
        bfr[n] = *(const short8*)(Bs + row * 64 + ((c16 ^ (row & 7)) << 3));
      }
      #pragma unroll
      for (int m = 0; m < 4; ++m)
        #pragma unroll
        for (int n = 0; n < 4; ++n)
          acc[m][n] = __builtin_amdgcn_mfma_f32_16x16x32_bf16(af[m], bfr[n], acc[m][n], 0, 0, 0);
    }
  }
  __syncthreads();

  // epilogue: cos -> k -> (K8, R8) byte planes in LDS, then coalesced stores
  unsigned char* CtK = (unsigned char*)smem;           // 16 KB
  unsigned char* CtR = ((unsigned char*)smem) + 16384; // 16 KB
  float a1v[4][4], b2v[4];
  #pragma unroll
  for (int m = 0; m < 4; ++m)
    #pragma unroll
    for (int q = 0; q < 4; ++q)
      a1v[m][q] = n1[(size_t)b * 1024 + ti + wr + m * 16 + ((lane >> 4) << 2) + q];
  #pragma unroll
  for (int n = 0; n < 4; ++n)
    b2v[n] = n2[(size_t)b * 1024 + tj + wc + n * 16 + (lane & 15)];
  #pragma unroll
  for (int m = 0; m < 4; ++m)
    #pragma unroll
    for (int n = 0; n < 4; ++n)
      #pragma unroll
      for (int q = 0; q < 4; ++q) {
        int rl = wr + m * 16 + ((lane >> 4) << 2) + q;
        int cl = wc + n * 16 + (lane & 15);
        float cosv = acc[m][n][q] / (a1v[m][q] * b2v[n] + EPSV);
        float kv = __expf(cosv - 1.0f);
        unsigned char q8 = enc1(kv);
        float kd = dec1(q8);
        float rr = kv / kd - 1.0f;
        CtK[rl * 128 + cl] = q8;
        CtR[rl * 128 + cl] = enc1(rr);
      }
  __syncthreads();
  size_t kbase = ((size_t)b << 20);
  #pragma unroll
  for (int i = 0; i < 4; ++i) {
    int idx = t + (i << 8);          // 1024 chunks of 16B per plane
    int row = idx >> 3, seg = idx & 7;
    size_t off = kbase + (size_t)(ti + row) * 1024 + tj + seg * 16;
    *(uint4*)(K8g + off) = ((const uint4*)CtK)[idx];
    *(uint4*)(R8g + off) = ((const uint4*)CtR)[idx];
  }
}

// ---------------------------------------------------------------- ktu0
// p0 = column sums of K8 per 256-row strip (u0=1). fp8 loads.
__global__ __launch_bounds__(512) void ktu0_kernel(
    const unsigned char* __restrict__ K8, _Float16* __restrict__ dst) {
  int bid = blockIdx.x;
  int b = bid >> 2, s = bid & 3;
  int t = threadIdx.x, lane = t & 63, w = t >> 6;
  __shared__ float plds[8][1024];  // 32 KB
  float pacc[16];
  #pragma unroll
  for (int k = 0; k < 16; ++k) pacc[k] = 0.f;
  const unsigned char* kp = K8 + ((size_t)b << 20) + (size_t)(s * 256 + w) * 1024 + lane * 16;
  #pragma unroll 2
  for (int it = 0; it < 32; ++it) {
    uint4 dk = *(const uint4*)(kp + (size_t)it * 8192);
    float kf[16];
    decode16(dk, kf);
    #pragma unroll
    for (int k = 0; k < 16; ++k) pacc[k] += kf[k];
  }
  *(float4*)&plds[w][lane * 16]      = *(float4*)&pacc[0];
  *(float4*)&plds[w][lane * 16 + 4]  = *(float4*)&pacc[4];
  *(float4*)&plds[w][lane * 16 + 8]  = *(float4*)&pacc[8];
  *(float4*)&plds[w][lane * 16 + 12] = *(float4*)&pacc[12];
  __syncthreads();
  #pragma unroll
  for (int p = 0; p < 2; ++p) {
    int col = (p << 9) + t;
    float sum = plds[0][col] + plds[1][col] + plds[2][col] + plds[3][col]
              + plds[4][col] + plds[5][col] + plds[6][col] + plds[7][col];
    dst[((size_t)b << 12) + (s << 10) + col] = (_Float16)sum;
  }
}

// ---------------------------------------------------------------- fused F
// Batch-2 rows + SW prefetch. RECON: K_rec = k8*(1+r8). FINAL: z+minmax only.
template<int RECON, int FINAL>
__global__ __launch_bounds__(512) void fused_kernel(
    const unsigned char* __restrict__ K8, const unsigned char* __restrict__ R8,
    const _Float16* __restrict__ src, _Float16* __restrict__ dst,
    float* __restrict__ zb, unsigned* __restrict__ mm) {
  int bid = blockIdx.x;
  int b = bid >> 2, s = bid & 3;
  int t = threadIdx.x, lane = t & 63, w = t >> 6;
  __shared__ float sv[1024];
  __shared__ float plds[8][1024];  // 32 KB
  __shared__ float red[16];
  #pragma unroll
  for (int p = 0; p < 2; ++p) {
    int col = (p << 9) + t;
    const _Float16* sp = src + ((size_t)b << 12) + col;
    float y = (float)sp[0] + (float)sp[1024] + (float)sp[2048] + (float)sp[3072];
    sv[col] = W1 / (y + EPSV);
  }
  __syncthreads();
  float svr[16];
  {
    float4 s0 = *(const float4*)&sv[lane * 16];
    float4 s1 = *(const float4*)&sv[lane * 16 + 4];
    float4 s2 = *(const float4*)&sv[lane * 16 + 8];
    float4 s3 = *(const float4*)&sv[lane * 16 + 12];
    svr[0] = s0.x;  svr[1] = s0.y;  svr[2]  = s0.z;  svr[3]  = s0.w;
    svr[4] = s1.x;  svr[5] = s1.y;  svr[6]  = s1.z;  svr[7]  = s1.w;
    svr[8] = s2.x;  svr[9] = s2.y;  svr[10] = s2.z;  svr[11] = s2.w;
    svr[12] = s3.x; svr[13] = s3.y; svr[14] = s3.z;  svr[15] = s3.w;
  }
  float pacc[16];
  #pragma unroll
  for (int k = 0; k < 16; ++k) pacc[k] = 0.f;
  float gmn = 3.4e38f, gmx = 0.f;
  const unsigned char* kp = K8 + ((size_t)b << 20) + (size_t)(s * 256 + w) * 1024 + lane * 16;
  const unsigned char* rp = R8 + ((size_t)b << 20) + (size_t)(s * 256 + w) * 1024 + lane * 16;
  // batch-2 rows with software prefetch (rows it=2p and 2p+1; stride 8 rows)
  uint4 c0 = *(const uint4*)(kp);
  uint4 c1 = *(const uint4*)(kp + 8192);
  uint4 r0, r1;
  if (RECON) { r0 = *(const uint4*)(rp); r1 = *(const uint4*)(rp + 8192); }
  for (int p = 0; p < 16; ++p) {
    uint4 n0, n1_, q0, q1;
    if (p < 15) {
      n0 = *(const uint4*)(kp + (size_t)(2 * p + 2) * 8192);
      n1_ = *(const uint4*)(kp + (size_t)(2 * p + 3) * 8192);
      if (RECON) {
        q0 = *(const uint4*)(rp + (size_t)(2 * p + 2) * 8192);
        q1 = *(const uint4*)(rp + (size_t)(2 * p + 3) * 8192);
      }
    }
    float kf0[16], kf1[16];
    decode16(c0, kf0);
    decode16(c1, kf1);
    if (RECON) {
      float rf0[16], rf1[16];
      decode16(r0, rf0);
      decode16(r1, rf1);
      #pragma unroll
      for (int k = 0; k < 16; ++k) {
        kf0[k] *= (1.0f + rf0[k]);
        kf1[k] *= (1.0f + rf1[k]);
      }
    }
    float d0 = 0.f, d1 = 0.f;
    #pragma unroll
    for (int k = 0; k < 16; ++k) {
      d0 += kf0[k] * svr[k];
      d1 += kf1[k] * svr[k];
    }
    #pragma unroll
    for (int off = 1; off < 64; off <<= 1) {
      d0 += __shfl_xor(d0, off, 64);
      d1 += __shfl_xor(d1, off, 64);
    }
    float u0 = W1 / (d0 + EPSV);
    float u1 = W1 / (d1 + EPSV);
    if (FINAL) {
      if (lane == 0) {
        zb[(b << 10) + s * 256 + w + (2 * p) * 8] = d0;
        zb[(b << 10) + s * 256 + w + (2 * p + 1) * 8] = d1;
      }
      #pragma unroll
      for (int k = 0; k < 16; ++k) {
        float g0 = u0 * kf0[k] * svr[k];
        float g1 = u1 * kf1[k] * svr[k];
        gmn = fminf(gmn, fminf(g0, g1));
        gmx = fmaxf(gmx, fmaxf(g0, g1));
      }
    } else {
      #pragma unroll
      for (int k = 0; k < 16; ++k)
        pacc[k] += kf0[k] * u0 + kf1[k] * u1;
    }
    c0 = n0; c1 = n1_;
    if (RECON) { r0 = q0; r1 = q1; }
  }
  if (!FINAL) {
    *(float4*)&plds[w][lane * 16]      = *(float4*)&pacc[0];
    *(float4*)&plds[w][lane * 16 + 4]  = *(float4*)&pacc[4];
    *(float4*)&plds[w][lane * 16 + 8]  = *(float4*)&pacc[8];
    *(float4*)&plds[w][lane * 16 + 12] = *(float4*)&pacc[12];
    __syncthreads();
    #pragma unroll
    for (int p = 0; p < 2; ++p) {
      int col = (p << 9) + t;
      float sum = plds[0][col] + plds[1][col] + plds[2][col] + plds[3][col]
                + plds[4][col] + plds[5][col] + plds[6][col] + plds[7][col];
      dst[((size_t)b << 12) + (s << 10) + col] = (_Float16)sum;
    }
  } else {
    #pragma unroll
    for (int off = 1; off < 64; off <<= 1) {
      gmn = fminf(gmn, __shfl_xor(gmn, off, 64));
      gmx = fmaxf(gmx, __shfl_xor(gmx, off, 64));
    }
    if (lane == 0) { red[w] = gmn; red[8 + w] = gmx; }
    __syncthreads();
    if (t == 0) {
      float m0 = red[0], m1 = red[8];
      #pragma unroll
      for (int i = 1; i < 8; ++i) { m0 = fminf(m0, red[i]); m1 = fmaxf(m1, red[8 + i]); }
      atomicMin(&mm[64 + b], __float_as_uint(m0));  // positive floats: uint order ok
      atomicMax(&mm[b],      __float_as_uint(m1));
    }
  }
}

// ---------------------------------------------------------------- fin
// out = ((G - gmin)/(gmax - gmin + eps)) * (-log K_rec)
__global__ __launch_bounds__(256) void fin_kernel(
    const unsigned char* __restrict__ K8, const unsigned char* __restrict__ R8,
    const _Float16* __restrict__ src, const float* __restrict__ zb,
    const unsigned* __restrict__ mm, float* __restrict__ out) {
  int bid = blockIdx.x;
  int b = bid >> 4, rg = bid & 15;
  int t = threadIdx.x, lane = t & 63, w = t >> 6;
  __shared__ float sv[1024];
  #pragma unroll
  for (int p = 0; p < 4; ++p) {
    int col = (p << 8) + t;
    const _Float16* sp = src + ((size_t)b << 12) + col;
    float y = (float)sp[0] + (float)sp[1024] + (float)sp[2048] + (float)sp[3072];
    sv[col] = W1 / (y + EPSV);
  }
  __syncthreads();
  float svr[16];
  {
    float4 s0 = *(const float4*)&sv[lane * 16];
    float4 s1 = *(const float4*)&sv[lane * 16 + 4];
    float4 s2 = *(const float4*)&sv[lane * 16 + 8];
    float4 s3 = *(const float4*)&sv[lane * 16 + 12];
    svr[0] = s0.x;  svr[1] = s0.y;  svr[2]  = s0.z;  svr[3]  = s0.w;
    svr[4] = s1.x;  svr[5] = s1.y;  svr[6]  = s1.z;  svr[7]  = s1.w;
    svr[8] = s2.x;  svr[9] = s2.y;  svr[10] = s2.z;  svr[11] = s2.w;
    svr[12] = s3.x; svr[13] = s3.y; svr[14] = s3.z;  svr[15] = s3.w;
  }
  float gmx = __uint_as_float(mm[b]);
  float gmn = __uint_as_float(mm[64 + b]);
  float scale = 1.0f / (gmx - gmn + EPSV);
  const unsigned char* kp = K8 + ((size_t)b << 20) + (size_t)(rg * 64 + w) * 1024 + lane * 16;
  const unsigned char* rp = R8 + ((size_t)b << 20) + (size_t)(rg * 64 + w) * 1024 + lane * 16;
  float* op = out + ((size_t)b << 20) + (size_t)(rg * 64 + w) * 1024 + lane * 16;
  for (int it = 0; it < 16; ++it) {
    int r = rg * 64 + w + it * 4;
    float u = W1 / (zb[b * 1024 + r] + EPSV);
    uint4 dk = *(const uint4*)(kp + (size_t)it * 4096);
    uint4 dr = *(const uint4*)(rp + (size_t)it * 4096);
    float kf[16], rf[16], o[16];
    decode16(dk, kf);
    decode16(dr, rf);
    #pragma unroll
    for (int k = 0; k < 16; ++k) {
      float krec = kf[k] * (1.0f + rf[k]);
      float g = u * krec * svr[k];
      o[k] = (g - gmn) * scale * (-__logf(krec));
    }
    *(float4*)(op + (size_t)it * 4096)      = *(float4*)&o[0];
    *(float4*)(op + (size_t)it * 4096 + 4)  = *(float4*)&o[4];
    *(float4*)(op + (size_t)it * 4096 + 8)  = *(float4*)&o[8];
    *(float4*)(op + (size_t)it * 4096 + 12) = *(float4*)&o[12];
  }
}

// ---------------------------------------------------------------- launch
extern "C" void kernel_launch(void* const* d_in, const int* in_sizes, int n_in,
                              void* d_out, int out_size, void* d_ws, size_t ws_size,
                              hipStream_t stream) {
  const float* x1 = (const float*)d_in[0];
  const float* x2 = (const float*)d_in[1];
  float* out = (float*)d_out;
  char* ws = (char*)d_ws;

  // ws layout (bytes)
  unsigned char* K8g = (unsigned char*)ws;                 // 67108864
  unsigned char* R8g = (unsigned char*)(ws + 67108864ULL); // 67108864
  float*    n1 = (float*)(ws + 134217728ULL);              // 262144 (reused as zb)
  float*    zb = (float*)(ws + 134217728ULL);
  float*    n2 = (float*)(ws + 134479872ULL);              // 262144
  _Float16* pA = (_Float16*)(ws + 134742016ULL);           // 524288
  _Float16* pB = (_Float16*)(ws + 135266304ULL);           // 524288
  unsigned* mm = (unsigned*)(ws + 135790592ULL);           // 512
  const size_t WS_NEED = 135791104ULL;                     // <= proven 136053248

  if (ws_size < WS_NEED) {
    float val = 100.0f + (float)(ws_size >> 20);
    diag_kernel<<<2048, 256, 0, stream>>>(out, val, out_size);
    return;
  }

  prep_kernel<<<32768, 256, 0, stream>>>(x1, x2, n1, n2, mm);
  gemm_kernel<<<4096, 256, 0, stream>>>(x1, x2, n1, n2, K8g, R8g);
  ktu0_kernel<<<256, 512, 0, stream>>>(K8g, pA);
  for (int k = 1; k <= 8; ++k) {
    _Float16* src = (k & 1) ? pA : pB;
    _Float16* dst = (k & 1) ? pB : pA;
    fused_kernel<0, 0><<<256, 512, 0, stream>>>(K8g, R8g, src, dst, zb, mm);
  }
  // k=9: reconstructed K for accuracy re-convergence
  fused_kernel<1, 0><<<256, 512, 0, stream>>>(K8g, R8g, pA, pB, zb, mm);
  // k=10 FINAL: reconstructed K; writes zb + minmax only
  fused_kernel<1, 1><<<256, 512, 0, stream>>>(K8g, R8g, pB, pA, zb, mm);
  fin_kernel<<<1024, 256, 0, stream>>>(K8g, R8g, pB, zb, mm, out);
}